// Round 5
// baseline (706.146 us; speedup 1.0000x reference)
//
#include <hip/hip_runtime.h>
#include <hip/hip_cooperative_groups.h>

namespace cg = cooperative_groups;

#define N_NODES 8192
#define CAP 128    // neighbor capacity; Binomial(8192,1/256): P(deg>128) ~ 0
#define ETILE 16   // nodes per MLP tile
constexpr int AST = 132;  // activation LDS row stride (floats), 16B-aligned
constexpr int WST = 129;  // weight LDS row stride (k-major), +1 pad

struct Params {
  const float *adj, *x, *mask;
  const float *w1, *b1, *w2, *b2, *wg, *bg, *wd, *bd;
  const float *wp1, *bp1, *wp2, *bp2, *wo, *bo;
  float *out;
  float *h, *msg, *g1, *dinv;
  int *cnt, *nbr;
};

// ---------------------------------------------------------------------------
// LDS-resident MLP layer for a tile of TILE nodes, 256 threads.
// A = [A0 | A1] split at KSPLIT. W is F x K row-major, staged k-major in
// 32-wide chunks. ACT = min(256, F*TILE) threads compute; RS rows per sweep.
// ---------------------------------------------------------------------------
template <int TILE, int K, int KSPLIT, int F, bool RELU, bool BIAS, bool SCALE>
__device__ __forceinline__ void layer_op(
    const float (*__restrict__ A0)[AST], const float (*__restrict__ A1)[AST],
    float (*__restrict__ Aout)[AST], float (*__restrict__ Wb)[WST],
    const float* __restrict__ W, const float* __restrict__ bias,
    float* __restrict__ gout, const float* __restrict__ rowscale,
    int n0, int t) {
  constexpr int KC = 32;
  constexpr int NCH = K / KC;
  constexpr int ACT = (F * TILE < 256) ? F * TILE : 256;
  constexpr int RS = ACT / F;     // rows per sweep
  constexpr int RPT = TILE / RS;  // accumulators per thread
  const int c = t % F;
  const int rb = t / F;  // valid when t < ACT
  float acc[RPT];
#pragma unroll
  for (int i = 0; i < RPT; ++i) acc[i] = 0.f;

  for (int ch = 0; ch < NCH; ++ch) {
#pragma unroll
    for (int i = 0; i < (F * KC + 255) / 256; ++i) {  // stage W chunk, k-major
      int lin = t + i * 256;
      if ((F * KC) % 256 == 0 || lin < F * KC) {
        int k = lin % KC, f = lin / KC;
        Wb[k][f] = W[(size_t)f * K + ch * KC + k];
      }
    }
    __syncthreads();
    if (t < ACT) {
      const float (*__restrict__ As)[AST] = (ch * KC < KSPLIT) ? A0 : A1;
      const int kb = (ch * KC < KSPLIT) ? ch * KC : ch * KC - KSPLIT;
#pragma unroll
      for (int kg = 0; kg < KC / 4; ++kg) {
        float w0 = Wb[kg * 4 + 0][c];
        float w1v = Wb[kg * 4 + 1][c];
        float w2v = Wb[kg * 4 + 2][c];
        float w3v = Wb[kg * 4 + 3][c];
#pragma unroll
        for (int i = 0; i < RPT; ++i) {
          const float4 a = *(const float4*)&As[rb + i * RS][kb + kg * 4];
          acc[i] = fmaf(a.x, w0, acc[i]);
          acc[i] = fmaf(a.y, w1v, acc[i]);
          acc[i] = fmaf(a.z, w2v, acc[i]);
          acc[i] = fmaf(a.w, w3v, acc[i]);
        }
      }
    }
    __syncthreads();
  }
  if (t < ACT) {
#pragma unroll
    for (int i = 0; i < RPT; ++i) {
      float v = acc[i];
      if (BIAS) v += bias[c];
      if (RELU) v = fmaxf(v, 0.f);
      int node = n0 + rb + i * RS;
      if (SCALE) v *= rowscale[node];
      if (Aout) Aout[rb + i * RS][c] = v;
      if (gout) gout[(size_t)node * F + c] = v;
    }
  }
}

// ---------------------------------------------------------------------------
// Single cooperative kernel: scan -> encode -> agg -> decode with grid.sync.
// ---------------------------------------------------------------------------
__global__ __launch_bounds__(256, 2) void fused_kernel(Params p) {
  __shared__ float bufA[ETILE][AST];
  __shared__ float bufB[ETILE][AST];
  __shared__ float bufH[ETILE][AST];
  __shared__ float Wb[32][WST];
  __shared__ int s_wt[4];
  cg::grid_group grid = cg::this_grid();
  const int t = threadIdx.x;
  const int nb = gridDim.x;

  // ======== Phase 1: adj scan -> cnt / nbr / dinv (double-buffered rows) ====
  {
    const uint4* adj4 = (const uint4*)p.adj;
    const int lane = t & 63;
    const int w = t >> 6;
    uint4 v[8], vn[8];
    int r = blockIdx.x;
    {
      const uint4* rp = adj4 + (size_t)r * (N_NODES / 4);
#pragma unroll
      for (int i = 0; i < 8; ++i) v[i] = rp[t + i * 256];
    }
    for (; r < N_NODES; r += nb) {
      const int rn = r + nb;
      if (rn < N_NODES) {  // prefetch next row while processing current
        const uint4* rp = adj4 + (size_t)rn * (N_NODES / 4);
#pragma unroll
        for (int i = 0; i < 8; ++i) vn[i] = rp[t + i * 256];
      }
      // branchless per-lane nonzero count
      int c = 0;
#pragma unroll
      for (int i = 0; i < 8; ++i)
        c += (v[i].x != 0u) + (v[i].y != 0u) + (v[i].z != 0u) + (v[i].w != 0u);
      // wave-inclusive prefix scan
      int incl = c;
#pragma unroll
      for (int s = 1; s < 64; s <<= 1) {
        int n = __shfl_up(incl, s);
        if (lane >= s) incl += n;
      }
      __syncthreads();  // protect s_wt reuse across rows
      if (lane == 63) s_wt[w] = incl;
      __syncthreads();
      int base = 0, total = 0;
#pragma unroll
      for (int wi = 0; wi < 4; ++wi) {
        int x = s_wt[wi];
        total += x;
        if (wi < w) base += x;
      }
      int off = base + incl - c;  // exclusive per-lane start
      // emit nonzero columns (loads all retired)
      int* nbr_row = p.nbr + (size_t)r * CAP;
#pragma unroll
      for (int i = 0; i < 8; ++i) {
        if (v[i].x | v[i].y | v[i].z | v[i].w) {
          const int col = (t + i * 256) * 4;
          if (v[i].x) { if (off < CAP) nbr_row[off] = col + 0; ++off; }
          if (v[i].y) { if (off < CAP) nbr_row[off] = col + 1; ++off; }
          if (v[i].z) { if (off < CAP) nbr_row[off] = col + 2; ++off; }
          if (v[i].w) { if (off < CAP) nbr_row[off] = col + 3; ++off; }
        }
      }
      if (t == 0) {
        p.cnt[r] = total;
        p.dinv[r] = rsqrtf((float)total + 1.0f);
      }
#pragma unroll
      for (int i = 0; i < 8; ++i) v[i] = vn[i];
    }
  }
  grid.sync();

  // ======== Phase 2: encoder x -> h1 -> h ; msg = (h@wg.T) * dinv ==========
  for (int tile = blockIdx.x; tile < N_NODES / ETILE; tile += nb) {
    const int n0 = tile * ETILE;
    if (t < 128) {  // stage x tile: 16x32 floats = 128 float4
      int row = t >> 3, k4 = (t & 7) * 4;
      *(float4*)&bufA[row][k4] = *(const float4*)&p.x[(size_t)(n0 + row) * 32 + k4];
    }
    layer_op<ETILE, 32, 32, 64, true, true, false>(bufA, nullptr, bufB, Wb, p.w1, p.b1, nullptr, nullptr, n0, t);
    layer_op<ETILE, 64, 64, 128, true, true, false>(bufB, nullptr, bufA, Wb, p.w2, p.b2, p.h, nullptr, n0, t);
    layer_op<ETILE, 128, 128, 128, false, false, true>(bufA, nullptr, nullptr, Wb, p.wg, nullptr, p.msg, p.dinv, n0, t);
    __syncthreads();
  }
  grid.sync();

  // ======== Phase 3: agg: g1 = relu(dinv_i*(msg'_i + sum msg'_j) + bg) =====
  // msg' already scaled by dinv. 2 groups x 4 rows per block-iter => ILP.
  {
    const int f = t & 127;
    const int g = t >> 7;  // 0..1
    for (int base = blockIdx.x * 8; base < N_NODES; base += nb * 8) {
      const int r0 = base + g * 4;
      float acc[4];
      int c[4];
      int cmax = 0;
#pragma unroll
      for (int k = 0; k < 4; ++k) {
        const int r = r0 + k;
        c[k] = p.cnt[r];
        acc[k] = p.msg[(size_t)r * 128 + f];  // self-loop term
        cmax = max(cmax, c[k]);
      }
      cmax = min(cmax, CAP);
      for (int i = 0; i < cmax; ++i) {
#pragma unroll
        for (int k = 0; k < 4; ++k) {
          const int cc = c[k];
          int ii = (i < cc) ? i : (cc > 0 ? cc - 1 : 0);
          int j = p.nbr[(size_t)(r0 + k) * CAP + ii] & (N_NODES - 1);
          float a = p.msg[(size_t)j * 128 + f];
          acc[k] += (i < cc) ? a : 0.f;
        }
      }
#pragma unroll
      for (int k = 0; k < 4; ++k) {
        const int r = r0 + k;
        float v = fmaf(p.dinv[r], acc[k], p.bg[f]);
        p.g1[(size_t)r * 128 + f] = fmaxf(v, 0.f);
      }
    }
  }
  grid.sync();

  // ======== Phase 4: decoder g1 -> g2 -> p1([g2|h]) -> p2 -> out * mask ====
  for (int tile = blockIdx.x; tile < N_NODES / ETILE; tile += nb) {
    const int n0 = tile * ETILE;
#pragma unroll
    for (int i = 0; i < 2; ++i) {  // stage g1 and h tiles (16x128 each)
      int lin = t + i * 256;
      int row = lin >> 5, k4 = (lin & 31) * 4;
      *(float4*)&bufA[row][k4] = *(const float4*)&p.g1[(size_t)(n0 + row) * 128 + k4];
      *(float4*)&bufH[row][k4] = *(const float4*)&p.h[(size_t)(n0 + row) * 128 + k4];
    }
    layer_op<ETILE, 128, 128, 128, true, true, false>(bufA, nullptr, bufB, Wb, p.wd, p.bd, nullptr, nullptr, n0, t);
    layer_op<ETILE, 256, 128, 128, true, true, false>(bufB, bufH, bufA, Wb, p.wp1, p.bp1, nullptr, nullptr, n0, t);
    layer_op<ETILE, 128, 128, 64, true, true, false>(bufA, nullptr, bufB, Wb, p.wp2, p.bp2, nullptr, nullptr, n0, t);
    layer_op<ETILE, 64, 64, 8, false, true, true>(bufB, nullptr, nullptr, Wb, p.wo, p.bo, p.out, p.mask, n0, t);
    __syncthreads();
  }
}

extern "C" void kernel_launch(void* const* d_in, const int* in_sizes, int n_in,
                              void* d_out, int out_size, void* d_ws, size_t ws_size,
                              hipStream_t stream) {
  Params pr;
  pr.adj = (const float*)d_in[1];
  pr.x   = (const float*)d_in[0];
  pr.mask = (const float*)d_in[2];
  pr.w1 = (const float*)d_in[3];  pr.b1 = (const float*)d_in[4];
  pr.w2 = (const float*)d_in[5];  pr.b2 = (const float*)d_in[6];
  pr.wg = (const float*)d_in[7];  pr.bg = (const float*)d_in[8];
  pr.wd = (const float*)d_in[9];  pr.bd = (const float*)d_in[10];
  pr.wp1 = (const float*)d_in[11]; pr.bp1 = (const float*)d_in[12];
  pr.wp2 = (const float*)d_in[13]; pr.bp2 = (const float*)d_in[14];
  pr.wo = (const float*)d_in[15]; pr.bo = (const float*)d_in[16];
  pr.out = (float*)d_out;

  float* ws = (float*)d_ws;
  pr.h    = ws; ws += (size_t)N_NODES * 128;
  pr.msg  = ws; ws += (size_t)N_NODES * 128;
  pr.g1   = ws; ws += (size_t)N_NODES * 128;
  pr.dinv = ws; ws += N_NODES;
  pr.cnt = (int*)ws; ws += N_NODES;
  pr.nbr = (int*)ws;  // N_NODES * CAP ints

  int maxb = 0;
  hipError_t e = hipOccupancyMaxActiveBlocksPerMultiprocessor(&maxb, fused_kernel, 256, 0);
  int nblocks = (e == hipSuccess && maxb >= 2) ? 512 : 256;  // grid-stride safe either way

  void* args[] = {&pr};
  hipLaunchCooperativeKernel((const void*)fused_kernel, dim3(nblocks), dim3(256),
                             args, 0, stream);
}

// Round 6
// 467.959 us; speedup vs baseline: 1.5090x; 1.5090x over previous
//
#include <hip/hip_runtime.h>

#define N_NODES 8192
#define CAP 128    // neighbor capacity; Binomial(8192,1/256): P(deg>128) ~ 0
#define ETILE 16   // nodes per MLP tile
constexpr int AST = 132;  // activation LDS row stride (floats), 16B-aligned
constexpr int WST = 129;  // weight LDS row stride (k-major), +1 pad

// ---------------------------------------------------------------------------
// Kernel 1: adj scan -> CSR. ONE ROW PER WAVE, zero barriers in the loop.
// Row = 4 chunks of 8 uint4/lane (8KB/chunk/wave); chunk-level software
// pipeline: prefetch chunk ch+1 while counting/emitting chunk ch. All
// bookkeeping is wave-private (shuffle prefix scan) -> no __syncthreads ->
// no vmcnt(0) drain -> prefetch actually overlaps latency.
// ---------------------------------------------------------------------------
__global__ __launch_bounds__(256, 4) void scan_kernel(
    const float* __restrict__ adj, int* __restrict__ cnt,
    int* __restrict__ nbr, float* __restrict__ dinv) {
  const int t = threadIdx.x;
  const int lane = t & 63;
  const int row = blockIdx.x * 4 + (t >> 6);
  const uint4* rowp = (const uint4*)(adj + (size_t)row * N_NODES);
  uint4 v[8], vn[8];
#pragma unroll
  for (int i = 0; i < 8; ++i) v[i] = rowp[i * 64 + lane];  // chunk 0
  int running = 0;
  int* nbr_row = nbr + (size_t)row * CAP;
  for (int ch = 0; ch < 4; ++ch) {
    if (ch < 3) {  // prefetch next chunk while consuming current
      const uint4* cp = rowp + (ch + 1) * 512;
#pragma unroll
      for (int i = 0; i < 8; ++i) vn[i] = cp[i * 64 + lane];
    }
    // branchless per-lane nonzero count of current chunk
    int c = 0;
#pragma unroll
    for (int i = 0; i < 8; ++i)
      c += (v[i].x != 0u) + (v[i].y != 0u) + (v[i].z != 0u) + (v[i].w != 0u);
    // wave-inclusive prefix scan (shuffles only; no barrier)
    int incl = c;
#pragma unroll
    for (int s = 1; s < 64; s <<= 1) {
      int n = __shfl_up(incl, s);
      if (lane >= s) incl += n;
    }
    int off = running + incl - c;       // exclusive per-lane start
    running += __shfl(incl, 63);        // add chunk total
    const int colbase = ch * 2048;
#pragma unroll
    for (int i = 0; i < 8; ++i) {
      if (v[i].x | v[i].y | v[i].z | v[i].w) {
        const int col = colbase + (i * 64 + lane) * 4;
        if (v[i].x) { if (off < CAP) nbr_row[off] = col + 0; ++off; }
        if (v[i].y) { if (off < CAP) nbr_row[off] = col + 1; ++off; }
        if (v[i].z) { if (off < CAP) nbr_row[off] = col + 2; ++off; }
        if (v[i].w) { if (off < CAP) nbr_row[off] = col + 3; ++off; }
      }
    }
#pragma unroll
    for (int i = 0; i < 8; ++i) v[i] = vn[i];
  }
  if (lane == 0) {
    cnt[row] = running;
    dinv[row] = rsqrtf((float)running + 1.0f);
  }
}

// ---------------------------------------------------------------------------
// LDS-resident MLP layer for a tile of TILE nodes, 256 threads.
// ---------------------------------------------------------------------------
template <int TILE, int K, int KSPLIT, int F, bool RELU, bool BIAS, bool SCALE>
__device__ __forceinline__ void layer_op(
    const float (*__restrict__ A0)[AST], const float (*__restrict__ A1)[AST],
    float (*__restrict__ Aout)[AST], float (*__restrict__ Wb)[WST],
    const float* __restrict__ W, const float* __restrict__ bias,
    float* __restrict__ gout, const float* __restrict__ rowscale,
    int n0, int t) {
  constexpr int KC = 32;
  constexpr int NCH = K / KC;
  constexpr int ACT = (F * TILE < 256) ? F * TILE : 256;
  constexpr int RS = ACT / F;
  constexpr int RPT = TILE / RS;
  const int c = t % F;
  const int rb = t / F;
  float acc[RPT];
#pragma unroll
  for (int i = 0; i < RPT; ++i) acc[i] = 0.f;

  for (int ch = 0; ch < NCH; ++ch) {
#pragma unroll
    for (int i = 0; i < (F * KC + 255) / 256; ++i) {  // stage W chunk, k-major
      int lin = t + i * 256;
      if ((F * KC) % 256 == 0 || lin < F * KC) {
        int k = lin % KC, f = lin / KC;
        Wb[k][f] = W[(size_t)f * K + ch * KC + k];
      }
    }
    __syncthreads();
    if (t < ACT) {
      const float (*__restrict__ As)[AST] = (ch * KC < KSPLIT) ? A0 : A1;
      const int kb = (ch * KC < KSPLIT) ? ch * KC : ch * KC - KSPLIT;
#pragma unroll
      for (int kg = 0; kg < KC / 4; ++kg) {
        float w0 = Wb[kg * 4 + 0][c];
        float w1v = Wb[kg * 4 + 1][c];
        float w2v = Wb[kg * 4 + 2][c];
        float w3v = Wb[kg * 4 + 3][c];
#pragma unroll
        for (int i = 0; i < RPT; ++i) {
          const float4 a = *(const float4*)&As[rb + i * RS][kb + kg * 4];
          acc[i] = fmaf(a.x, w0, acc[i]);
          acc[i] = fmaf(a.y, w1v, acc[i]);
          acc[i] = fmaf(a.z, w2v, acc[i]);
          acc[i] = fmaf(a.w, w3v, acc[i]);
        }
      }
    }
    __syncthreads();
  }
  if (t < ACT) {
#pragma unroll
    for (int i = 0; i < RPT; ++i) {
      float v = acc[i];
      if (BIAS) v += bias[c];
      if (RELU) v = fmaxf(v, 0.f);
      int node = n0 + rb + i * RS;
      if (SCALE) v *= rowscale[node];
      if (Aout) Aout[rb + i * RS][c] = v;
      if (gout) gout[(size_t)node * F + c] = v;
    }
  }
}

// ---------------------------------------------------------------------------
// Kernel 2: encoder x -> h1 -> h ; msg = (h @ wg.T) * dinv  (512 blocks)
// ---------------------------------------------------------------------------
__global__ __launch_bounds__(256) void encode_kernel(
    const float* __restrict__ x,
    const float* __restrict__ w1, const float* __restrict__ b1,
    const float* __restrict__ w2, const float* __restrict__ b2,
    const float* __restrict__ wg, const float* __restrict__ dinv,
    float* __restrict__ h_out, float* __restrict__ msg_out) {
  __shared__ float bufA[ETILE][AST];
  __shared__ float bufB[ETILE][AST];
  __shared__ float Wb[32][WST];
  const int t = threadIdx.x;
  const int n0 = blockIdx.x * ETILE;
  if (t < 128) {  // stage x tile: 16x32 floats = 128 float4
    int row = t >> 3, k4 = (t & 7) * 4;
    *(float4*)&bufA[row][k4] = *(const float4*)&x[(size_t)(n0 + row) * 32 + k4];
  }
  layer_op<ETILE, 32, 32, 64, true, true, false>(bufA, nullptr, bufB, Wb, w1, b1, nullptr, nullptr, n0, t);
  layer_op<ETILE, 64, 64, 128, true, true, false>(bufB, nullptr, bufA, Wb, w2, b2, h_out, nullptr, n0, t);
  layer_op<ETILE, 128, 128, 128, false, false, true>(bufA, nullptr, nullptr, Wb, wg, nullptr, msg_out, dinv, n0, t);
}

// ---------------------------------------------------------------------------
// Kernel 3: agg. 2 rows per 256-thread block, barrier-free gathers.
// g1 = relu(dinv_i * (msg'_i + sum_j msg'_j) + bg), msg' pre-scaled by dinv.
// ---------------------------------------------------------------------------
__global__ __launch_bounds__(256) void agg_kernel(
    const int* __restrict__ cnt, const int* __restrict__ nbr,
    const float* __restrict__ msg, const float* __restrict__ dinv,
    const float* __restrict__ bg, const float* __restrict__ adj,
    float* __restrict__ g1) {
  const int t = threadIdx.x;
  const int f = t & 127;
  const int row = blockIdx.x * 2 + (t >> 7);
  float acc = msg[(size_t)row * 128 + f];  // self-loop term
  const int c = cnt[row];
  if (c <= CAP) {
    int i = 0;
    for (; i + 4 <= c; i += 4) {
      int j0 = nbr[(size_t)row * CAP + i + 0];
      int j1 = nbr[(size_t)row * CAP + i + 1];
      int j2 = nbr[(size_t)row * CAP + i + 2];
      int j3 = nbr[(size_t)row * CAP + i + 3];
      float a0 = msg[(size_t)j0 * 128 + f];
      float a1 = msg[(size_t)j1 * 128 + f];
      float a2 = msg[(size_t)j2 * 128 + f];
      float a3 = msg[(size_t)j3 * 128 + f];
      acc += (a0 + a1) + (a2 + a3);
    }
    for (; i < c; ++i) {
      int j = nbr[(size_t)row * CAP + i];
      acc += msg[(size_t)j * 128 + f];
    }
  } else {  // statistically unreachable dense fallback
    for (int col = 0; col < N_NODES; ++col) {
      if (adj[(size_t)row * N_NODES + col] != 0.f) acc += msg[(size_t)col * 128 + f];
    }
  }
  float v = fmaf(dinv[row], acc, bg[f]);
  g1[(size_t)row * 128 + f] = fmaxf(v, 0.f);
}

// ---------------------------------------------------------------------------
// Kernel 4: decoder g1 -> g2 -> p1([g2|h]) -> p2 -> out * mask  (512 blocks)
// ---------------------------------------------------------------------------
__global__ __launch_bounds__(256) void decode_kernel(
    const float* __restrict__ g1, const float* __restrict__ h,
    const float* __restrict__ wd, const float* __restrict__ bd,
    const float* __restrict__ wp1, const float* __restrict__ bp1,
    const float* __restrict__ wp2, const float* __restrict__ bp2,
    const float* __restrict__ wo, const float* __restrict__ bo,
    const float* __restrict__ mask, float* __restrict__ out) {
  __shared__ float bufA[ETILE][AST];
  __shared__ float bufB[ETILE][AST];
  __shared__ float bufH[ETILE][AST];
  __shared__ float Wb[32][WST];
  const int t = threadIdx.x;
  const int n0 = blockIdx.x * ETILE;
#pragma unroll
  for (int i = 0; i < 2; ++i) {  // stage g1 and h tiles (16x128 each)
    int lin = t + i * 256;
    int row = lin >> 5, k4 = (lin & 31) * 4;
    *(float4*)&bufA[row][k4] = *(const float4*)&g1[(size_t)(n0 + row) * 128 + k4];
    *(float4*)&bufH[row][k4] = *(const float4*)&h[(size_t)(n0 + row) * 128 + k4];
  }
  layer_op<ETILE, 128, 128, 128, true, true, false>(bufA, nullptr, bufB, Wb, wd, bd, nullptr, nullptr, n0, t);
  layer_op<ETILE, 256, 128, 128, true, true, false>(bufB, bufH, bufA, Wb, wp1, bp1, nullptr, nullptr, n0, t);
  layer_op<ETILE, 128, 128, 64, true, true, false>(bufA, nullptr, bufB, Wb, wp2, bp2, nullptr, nullptr, n0, t);
  layer_op<ETILE, 64, 64, 8, false, true, true>(bufB, nullptr, nullptr, Wb, wo, bo, out, mask, n0, t);
}

extern "C" void kernel_launch(void* const* d_in, const int* in_sizes, int n_in,
                              void* d_out, int out_size, void* d_ws, size_t ws_size,
                              hipStream_t stream) {
  const float* x    = (const float*)d_in[0];
  const float* adj  = (const float*)d_in[1];
  const float* mask = (const float*)d_in[2];
  const float* w1   = (const float*)d_in[3];
  const float* b1   = (const float*)d_in[4];
  const float* w2   = (const float*)d_in[5];
  const float* b2   = (const float*)d_in[6];
  const float* wg   = (const float*)d_in[7];
  const float* bg   = (const float*)d_in[8];
  const float* wd   = (const float*)d_in[9];
  const float* bd   = (const float*)d_in[10];
  const float* wp1  = (const float*)d_in[11];
  const float* bp1  = (const float*)d_in[12];
  const float* wp2  = (const float*)d_in[13];
  const float* bp2  = (const float*)d_in[14];
  const float* wo   = (const float*)d_in[15];
  const float* bo   = (const float*)d_in[16];
  float* out = (float*)d_out;

  float* ws = (float*)d_ws;
  float* h    = ws; ws += (size_t)N_NODES * 128;
  float* msg  = ws; ws += (size_t)N_NODES * 128;
  float* g1   = ws; ws += (size_t)N_NODES * 128;
  float* dinv = ws; ws += N_NODES;
  int* cnt = (int*)ws; ws += N_NODES;
  int* nbr = (int*)ws;  // N_NODES * CAP ints

  scan_kernel<<<N_NODES / 4, 256, 0, stream>>>(adj, cnt, nbr, dinv);
  encode_kernel<<<N_NODES / ETILE, 256, 0, stream>>>(x, w1, b1, w2, b2, wg, dinv, h, msg);
  agg_kernel<<<N_NODES / 2, 256, 0, stream>>>(cnt, nbr, msg, dinv, bg, adj, g1);
  decode_kernel<<<N_NODES / ETILE, 256, 0, stream>>>(
      g1, h, wd, bd, wp1, bp1, wp2, bp2, wo, bo, mask, out);
}